// Round 8
// baseline (420.948 us; speedup 1.0000x reference)
//
#include <hip/hip_runtime.h>
#include <math.h>

#define SQ 4096
#define DD 1024
#define TRI 528          // causal 128x128 tiles in a 32x32 grid

typedef _Float16 f16;
typedef f16 f16x8 __attribute__((ext_vector_type(8)));
typedef f16 f16x4 __attribute__((ext_vector_type(4)));
typedef float f32x4 __attribute__((ext_vector_type(4)));

__device__ __forceinline__ float waveMax(float v) {
#pragma unroll
    for (int o = 32; o > 0; o >>= 1) v = fmaxf(v, __shfl_down(v, o, 64));
    return v;
}
__device__ __forceinline__ float waveSum(float v) {
#pragma unroll
    for (int o = 32; o > 0; o >>= 1) v += __shfl_down(v, o, 64);
    return v;
}

__device__ __forceinline__ void gl_lds16(const f16* g, f16* l) {
    __builtin_amdgcn_global_load_lds(
        (const __attribute__((address_space(1))) void*)g,
        (__attribute__((address_space(3))) void*)l, 16, 0, 0);
}

// Wave w stages NRW rows of a [*,32] f16 tile into LDS row-major [rows][32].
template<int NRW>
__device__ __forceinline__ void stage(const f16* src, int ldk, f16* lds, int w, int lane) {
    const int r0 = w * NRW + (lane >> 2);
    const f16* g = src + (size_t)r0 * ldk + ((lane & 3) << 3);
    f16* l = lds + w * NRW * 32;
    gl_lds16(g, l);
    if (NRW == 32) gl_lds16(g + (size_t)ldk * 16, l + 16 * 32);
}

// Flatmm-style TN GEMM: A staged via gl_lds into double-buffered LDS (2x reuse
// within block); B fragments loaded DIRECT global->VGPR (L2-served), prefetched
// one 32-k chunk ahead so a full chunk of MFMAs covers the load latency.
// One __syncthreads per chunk; its implicit drain waits loads issued a full
// chunk earlier (near-free). All kend values are multiples of 64 -> 2x-unrolled
// loop with role-swapped register sets (no inter-iter register copies).
// MODE 0: merged QKV projection, 128x128, grid (24,32).
// MODE 1: QK^T split-K=2, packed-triangular f32 partials, grid 1056 (plain order).
// MODE 2: PV, 64x128, A=P packed-triangular, B=Vt, grid (64,8) longest-first.
template<int MODE>
__global__ __launch_bounds__(256)
void gemm_k(const f16* __restrict__ Ah, const f16* __restrict__ Al,
            const f16* __restrict__ Bh, const f16* __restrict__ Bl,
            float* __restrict__ Cf,
            f16* __restrict__ Qh, f16* __restrict__ Ql,
            f16* __restrict__ Kh, f16* __restrict__ Kl,
            f16* __restrict__ Vt, float scale)
{
    constexpr int TM = (MODE == 2) ? 64 : 128;
    constexpr int NI = (MODE == 2) ? 2 : 4;       // 16-col frags per wave
    constexpr int AH = TM * 32;                   // f16 per A tile (hi or lo)
    constexpr bool ALO = (MODE != 2);             // lo-part of A may be staged
    constexpr int ABUF = ALO ? 2 * AH : AH;       // per-stage LDS footprint

    __shared__ f16 sm[2 * ABUF];

    int bm, bn, tri = 0, half = 0;
    if (MODE == 1) {
        const int lin = blockIdx.x;               // plain order (R7 swizzle regressed)
        half = lin & 1;
        tri = lin >> 1;
        bm = (int)((sqrtf(8.f * (float)tri + 1.f) - 1.f) * 0.5f);
        while ((bm + 1) * (bm + 2) / 2 <= tri) ++bm;
        while (bm * (bm + 1) / 2 > tri) --bm;
        bn = tri - bm * (bm + 1) / 2;
    } else if (MODE == 2) {
        bm = 63 - (int)blockIdx.x;                // longest blocks first
        bn = blockIdx.y;
    } else {
        bn = blockIdx.x; bm = blockIdx.y;
    }

    const int m0 = bm * TM;
    const int n0 = bn << 7;
    const int lda = (MODE == 2) ? 128 : DD;       // MODE2 A = packed tile rows
    const int ldb = (MODE == 2) ? SQ : DD;
    const int kst = (MODE == 1) ? (half << 9) : 0;
    const int kend = (MODE == 1) ? (kst + 512)
                   : (MODE == 2) ? (((bm >> 1) + 1) << 7) : DD;
    const bool dolo = (MODE == 1) || (MODE == 0 && bn < 16);

    const int tid = threadIdx.x;
    const int w = tid >> 6, lane = tid & 63;
    const int wr = (MODE == 2) ? 0 : ((w >> 1) << 6);
    const int wc = (MODE == 2) ? (w << 5) : ((w & 1) << 6);
    const int fcol = lane & 15, quad = lane >> 4;

    f32x4 acc[4][NI];
#pragma unroll
    for (int i = 0; i < 4; ++i)
#pragma unroll
        for (int j = 0; j < NI; ++j) acc[i][j] = (f32x4){0.f, 0.f, 0.f, 0.f};

    const int bmT = (MODE == 2) ? (bm >> 1) : 0;
    const size_t triRow = (MODE == 2) ? (size_t)(bmT * (bmT + 1) / 2) : 0;
    const f16* BbH = Bh + (size_t)n0 * ldb;
    const f16* BbL = dolo ? Bl + (size_t)n0 * ldb : nullptr;

    // stage A chunk kk into LDS buffer b
    auto stageA = [&](int b, int kk) {
        f16* dst = sm + b * ABUF;
        const f16* as;
        if (MODE == 2) {
            as = Ah + ((triRow + (size_t)(kk >> 7)) << 14)
                    + ((size_t)(m0 & 127) << 7) + (kk & 127);
        } else {
            as = Ah + (size_t)m0 * DD + kk;
        }
        stage<TM / 4>(as, lda, dst, w, lane);
        if (ALO && dolo) stage<TM / 4>(Al + (size_t)m0 * DD + kk, DD, dst + AH, w, lane);
    };
    // direct global->VGPR B fragments for chunk kk
    auto loadB = [&](f16x8* dh, f16x8* dl, int kk) {
#pragma unroll
        for (int in = 0; in < NI; ++in) {
            const size_t off = (size_t)(wc + (in << 4) + fcol) * ldb + kk + (quad << 3);
            dh[in] = *(const f16x8*)(BbH + off);
            if (dolo) dl[in] = *(const f16x8*)(BbL + off);
        }
    };
    // 32-k chunk of MFMAs from LDS buffer b + B register set
    auto chunk = [&](int b, const f16x8* bh, const f16x8* bl) {
        const f16* base = sm + b * ABUF;
#pragma unroll
        for (int im = 0; im < 4; ++im) {
            const int off = ((wr + (im << 4) + fcol) << 5) + (quad << 3);
            f16x8 ah = *(const f16x8*)&base[off];
            f16x8 al;
            if (dolo) al = *(const f16x8*)&base[AH + off];
#pragma unroll
            for (int in = 0; in < NI; ++in) {
                if (dolo) {
                    acc[im][in] = __builtin_amdgcn_mfma_f32_16x16x32_f16(ah, bl[in], acc[im][in], 0, 0, 0);
                    acc[im][in] = __builtin_amdgcn_mfma_f32_16x16x32_f16(al, bh[in], acc[im][in], 0, 0, 0);
                }
                acc[im][in] = __builtin_amdgcn_mfma_f32_16x16x32_f16(ah, bh[in], acc[im][in], 0, 0, 0);
            }
        }
    };

    f16x8 b0h[NI], b0l[NI], b1h[NI], b1l[NI];
    stageA(0, kst);
    loadB(b0h, b0l, kst);

    for (int k0 = kst; k0 < kend; k0 += 64) {
        __syncthreads();                          // buf0 ready; prior reads retired
        stageA(1, k0 + 32);                       // always valid: kend multiple of 64
        loadB(b1h, b1l, k0 + 32);
        chunk(0, b0h, b0l);
        __syncthreads();                          // buf1 ready
        if (k0 + 64 < kend) {
            stageA(0, k0 + 64);
            loadB(b0h, b0l, k0 + 64);
        }
        chunk(1, b1h, b1l);
    }

    // C/D layout: col = lane&15, row = quad*4 + r  [m89-verified]
#pragma unroll
    for (int im = 0; im < 4; ++im) {
#pragma unroll
        for (int in = 0; in < NI; ++in) {
            if (MODE == 0) {
                const int region = bn >> 3;                       // 0=Q 1=K 2=V
                const int colL = ((bn & 7) << 7) + wc + (in << 4) + fcol;
                if (region == 2) {
                    const int tc = m0 + wr + (im << 4) + (quad << 2);
                    f16x4 o;
#pragma unroll
                    for (int r = 0; r < 4; ++r) o[r] = (f16)acc[im][in][r];
                    *(f16x4*)&Vt[(size_t)colL * SQ + tc] = o;
                } else {
                    f16* Hh = region ? Kh : Qh;
                    f16* Hl = region ? Kl : Ql;
#pragma unroll
                    for (int r = 0; r < 4; ++r) {
                        const int row = m0 + wr + (im << 4) + (quad << 2) + r;
                        const float v = acc[im][in][r];
                        const f16 h = (f16)v;
                        Hh[(size_t)row * DD + colL] = h;
                        Hl[(size_t)row * DD + colL] = (f16)(v - (float)h);
                    }
                }
            } else if (MODE == 1) {
                float* Cp = Cf + (((size_t)half * TRI + tri) << 14);
#pragma unroll
                for (int r = 0; r < 4; ++r) {
                    const int rl = wr + (im << 4) + (quad << 2) + r;
                    const int cl = wc + (in << 4) + fcol;
                    Cp[(rl << 7) + cl] = acc[im][in][r] * scale;
                }
            } else {
#pragma unroll
                for (int r = 0; r < 4; ++r) {
                    const int row = m0 + wr + (im << 4) + (quad << 2) + r;
                    const int col = n0 + wc + (in << 4) + fcol;
                    Cf[(size_t)row * DD + col] = acc[im][in][r];
                }
            }
        }
    }
}

// Fused pre-pass: blocks [0,4096) split x into f16 hi/lo; blocks [4096,4864)
// transpose+split the 3 weight matrices into one [3072,1024] hi/lo pair.
__global__ __launch_bounds__(256)
void prepass(const float* __restrict__ x,
             const float* __restrict__ W0, const float* __restrict__ W1,
             const float* __restrict__ W2,
             f16* __restrict__ xh, f16* __restrict__ xl,
             f16* __restrict__ Th0, f16* __restrict__ Tl0)
{
    __shared__ float t[64][65];
    const int id = blockIdx.x;
    const int tid = threadIdx.x;

    if (id < 4096) {
        const int i = (id * 256 + tid) * 4;
        const float4 v = *(const float4*)(x + i);
        const f16 h0 = (f16)v.x, h1 = (f16)v.y, h2 = (f16)v.z, h3 = (f16)v.w;
        f16x4 hv = {h0, h1, h2, h3};
        f16x4 lv = {(f16)(v.x - (float)h0), (f16)(v.y - (float)h1),
                    (f16)(v.z - (float)h2), (f16)(v.w - (float)h3)};
        *(f16x4*)(xh + i) = hv;
        *(f16x4*)(xl + i) = lv;
        return;
    }

    const int tt = id - 4096;
    const int z = tt >> 8, r8 = tt & 255;
    const float* W = (z == 0) ? W0 : (z == 1) ? W1 : W2;
    f16* Th = Th0 + (size_t)z * DD * DD;
    f16* Tl = Tl0 + (size_t)z * DD * DD;
    const int n0 = (r8 & 15) << 6, k0 = (r8 >> 4) << 6;
    const int tx = tid & 63, ty = tid >> 6;
    for (int r = ty; r < 64; r += 4) t[r][tx] = W[(size_t)(k0 + r) * DD + n0 + tx];
    __syncthreads();
    for (int r = ty; r < 64; r += 4) {
        const float v = t[tx][r];
        const f16 h = (f16)v;
        Th[(size_t)(n0 + r) * DD + k0 + tx] = h;
        Tl[(size_t)(n0 + r) * DD + k0 + tx] = (f16)(v - (float)h);
    }
}

// Row-wise causal softmax over packed-triangular split-K partials, vectorized.
__global__ __launch_bounds__(256)
void softmax_causal(const float* __restrict__ A0, f16* __restrict__ P)
{
    const int i = blockIdx.x;
    const int n = i + 1;
    const int tid = threadIdx.x, w = tid >> 6, lane = tid & 63;
    __shared__ float redM[4], redS[4];
    __shared__ float rowbuf[SQ];                 // 16 KB merged-logit stash

    const int bmI = i >> 7;
    const size_t base = ((size_t)(bmI * (bmI + 1) / 2) << 14) + ((size_t)(i & 127) << 7);
    const float* A1 = A0 + ((size_t)TRI << 14);

    const int nv = n >> 2;                       // full float4 groups
    float m = -INFINITY;
    for (int g = tid; g < nv; g += 256) {
        const int j = g << 2;
        const size_t a = base + ((size_t)(j >> 7) << 14) + (j & 127);
        const float4 v0 = *(const float4*)(A0 + a);
        const float4 v1 = *(const float4*)(A1 + a);
        float4 v = make_float4(v0.x + v1.x, v0.y + v1.y, v0.z + v1.z, v0.w + v1.w);
        *(f32x4*)&rowbuf[j] = (f32x4){v.x, v.y, v.z, v.w};
        m = fmaxf(m, fmaxf(fmaxf(v.x, v.y), fmaxf(v.z, v.w)));
    }
    for (int j = (nv << 2) + tid; j < n; j += 256) {
        const size_t a = base + ((size_t)(j >> 7) << 14) + (j & 127);
        const float v = A0[a] + A1[a];
        rowbuf[j] = v;
        m = fmaxf(m, v);
    }
    m = waveMax(m);
    if (lane == 0) redM[w] = m;
    __syncthreads();
    const float mAll = fmaxf(fmaxf(redM[0], redM[1]), fmaxf(redM[2], redM[3]));

    float s = 0.f;
    for (int g = tid; g < nv; g += 256) {
        const int j = g << 2;
        f32x4 v = *(f32x4*)&rowbuf[j];
        v[0] = __expf(v[0] - mAll); v[1] = __expf(v[1] - mAll);
        v[2] = __expf(v[2] - mAll); v[3] = __expf(v[3] - mAll);
        *(f32x4*)&rowbuf[j] = v;
        s += v[0] + v[1] + v[2] + v[3];
    }
    for (int j = (nv << 2) + tid; j < n; j += 256) {
        const float e = __expf(rowbuf[j] - mAll);
        rowbuf[j] = e;
        s += e;
    }
    s = waveSum(s);
    if (lane == 0) redS[w] = s;
    __syncthreads();
    const float inv = 1.0f / (redS[0] + redS[1] + redS[2] + redS[3]);

    const int kmax = (bmI + 1) << 7;             // P zero-fill boundary
    for (int g = tid; g < nv; g += 256) {
        const int j = g << 2;
        const size_t a = base + ((size_t)(j >> 7) << 14) + (j & 127);
        const f32x4 v = *(const f32x4*)&rowbuf[j];
        f16x4 o = {(f16)(v[0] * inv), (f16)(v[1] * inv),
                   (f16)(v[2] * inv), (f16)(v[3] * inv)};
        *(f16x4*)&P[a] = o;
    }
    for (int j = (nv << 2) + tid; j < kmax; j += 256) {
        const size_t a = base + ((size_t)(j >> 7) << 14) + (j & 127);
        P[a] = (j < n) ? (f16)(rowbuf[j] * inv) : (f16)0.f;
    }
}

extern "C" void kernel_launch(void* const* d_in, const int* in_sizes, int n_in,
                              void* d_out, int out_size, void* d_ws, size_t ws_size,
                              hipStream_t stream)
{
    const float* x  = (const float*)d_in[0];
    const float* Wq = (const float*)d_in[1];
    const float* Wk = (const float*)d_in[2];
    const float* Wv = (const float*)d_in[3];
    float* out = (float*)d_out;

    // workspace carve (~155 MB)
    char* p = (char*)d_ws;
    auto take = [&](size_t bytes) { void* r = (void*)p; p += (bytes + 255) & ~(size_t)255; return r; };
    const size_t SD = (size_t)SQ * DD;          // 4M elems
    f16* xh  = (f16*)take(SD * 2);
    f16* xl  = (f16*)take(SD * 2);
    f16* Wth = (f16*)take((size_t)3 * DD * DD * 2);   // [3072][1024]
    f16* Wtl = (f16*)take((size_t)3 * DD * DD * 2);
    f16* Qh  = (f16*)take(SD * 2);
    f16* Ql  = (f16*)take(SD * 2);
    f16* Kh  = (f16*)take(SD * 2);
    f16* Kl  = (f16*)take(SD * 2);
    f16* Vt  = (f16*)take(SD * 2);              // [DD][SQ]
    float* attn = (float*)take((size_t)2 * TRI * 16384 * 4);  // split-K partials, packed
    f16* P   = (f16*)take((size_t)TRI * 16384 * 2);           // packed triangular

    const dim3 blk(256);

    prepass<<<dim3(4096 + 768), blk, 0, stream>>>(x, Wq, Wk, Wv, xh, xl, Wth, Wtl);

    // Merged QKV projection: 768 blocks
    gemm_k<0><<<dim3(24, SQ / 128), blk, 0, stream>>>(
        xh, xl, Wth, Wtl, nullptr, Qh, Ql, Kh, Kl, Vt, 1.0f);

    // attn partials = Q @ K^T / 32 : split-K=2, 1056 blocks
    gemm_k<1><<<dim3(2 * TRI), blk, 0, stream>>>(
        Qh, Ql, Kh, Kl, attn, nullptr, nullptr, nullptr, nullptr, nullptr, 0.03125f);

    softmax_causal<<<dim3(SQ), blk, 0, stream>>>(attn, P);

    // out = P @ V : grid (64,8), longest-first
    gemm_k<2><<<dim3(SQ / 64, DD / 128), blk, 0, stream>>>(
        P, nullptr, Vt, nullptr, out, nullptr, nullptr, nullptr, nullptr, nullptr, 1.0f);
}

// Round 9
// 336.631 us; speedup vs baseline: 1.2505x; 1.2505x over previous
//
#include <hip/hip_runtime.h>
#include <math.h>

#define SQ 4096
#define DD 1024
#define TRI 528          // causal 128x128 tiles in a 32x32 grid

typedef _Float16 f16;
typedef f16 f16x8 __attribute__((ext_vector_type(8)));
typedef f16 f16x4 __attribute__((ext_vector_type(4)));
typedef float f32x4 __attribute__((ext_vector_type(4)));
typedef float f32x16 __attribute__((ext_vector_type(16)));

__device__ __forceinline__ float waveMax(float v) {
#pragma unroll
    for (int o = 32; o > 0; o >>= 1) v = fmaxf(v, __shfl_down(v, o, 64));
    return v;
}
__device__ __forceinline__ float waveSum(float v) {
#pragma unroll
    for (int o = 32; o > 0; o >>= 1) v += __shfl_down(v, o, 64);
    return v;
}

__device__ __forceinline__ void gl_lds16(const f16* g, f16* l) {
    __builtin_amdgcn_global_load_lds(
        (const __attribute__((address_space(1))) void*)g,
        (__attribute__((address_space(3))) void*)l, 16, 0, 0);
}

// Staging with source-side chunk permutation: physical 16B chunk p of LDS row r
// holds LOGICAL chunk p ^ (r&3). gl_lds dest is fixed (lane L -> row L/4,
// phys chunk L%3): we permute the GLOBAL source chunk. Same 64B segments per
// 4-lane group -> coalescing unchanged (verified legal+neutral in R3).
// This spreads the 32x32-fragment ds_reads across all 8 LDS bank groups.
template<int NRW>
__device__ __forceinline__ void stage(const f16* src, int ldk, f16* lds, int w, int lane) {
    const int lc = (lane & 3) ^ ((lane >> 2) & 3);
    const f16* g = src + (size_t)(w * NRW + (lane >> 2)) * ldk + (lc << 3);
    f16* l = lds + w * NRW * 32;
    gl_lds16(g, l);
    if (NRW == 32) gl_lds16(g + (size_t)ldk * 16, l + 16 * 32);  // +16 rows: same phase
}

// LDS addr (f16 units) of the 8-elem fragment: tile-local row rr, logical chunk c
__device__ __forceinline__ int frag_off(int rr, int c) {
    return (rr << 5) + ((((c ^ rr) & 3)) << 3);
}

// Unified TN GEMM, 32x32x16 MFMA (+15% rate vs 16x16x32, half the instructions).
// A/B frag: elem j of lane L = M[rr = L&31][k = (L>>5)*8 + j]  (analogy to the
// verified 16x16 mapping). C/D: col = lane&31, row = (reg&3)+8*(reg>>2)+4*(lane>>5)
// [m74/m101-verified].
// MODE 0: merged QKV projection, 128x128, grid (24,32). bn<16: split3+split-store;
//         bn>=16: V, hi-only + transposed f16 store.
// MODE 1: QK^T split-K=2, packed-triangular f32 partials, grid 1056, plain order.
// MODE 2: PV, 64x128, BK=64, A=P packed-triangular, grid (64,8) longest-first.
template<int MODE>
__global__ __launch_bounds__(256)
void gemm_k(const f16* __restrict__ Ah, const f16* __restrict__ Al,
            const f16* __restrict__ Bh, const f16* __restrict__ Bl,
            float* __restrict__ Cf,
            f16* __restrict__ Qh, f16* __restrict__ Ql,
            f16* __restrict__ Kh, f16* __restrict__ Kl,
            f16* __restrict__ Vt, float scale)
{
    constexpr int TM = (MODE == 2) ? 64 : 128;
    constexpr int NI = (MODE == 2) ? 1 : 2;       // 32-col frags per wave
    constexpr int H  = (MODE == 2) ? 2 : 1;       // BK/32 half-tiles
    constexpr int AH = TM * 32;                   // f16 per A half-tile
    constexpr int BH = 128 * 32;
    constexpr int SMSZ = (MODE == 2) ? H * (AH + BH) : 2 * H * (AH + BH);

    int bm, bn, tri = 0, half = 0;
    if (MODE == 1) {
        const int lin = blockIdx.x;               // plain order (R7 swizzle regressed)
        half = lin & 1;
        tri = lin >> 1;
        bm = (int)((sqrtf(8.f * (float)tri + 1.f) - 1.f) * 0.5f);
        while ((bm + 1) * (bm + 2) / 2 <= tri) ++bm;
        while (bm * (bm + 1) / 2 > tri) --bm;
        bn = tri - bm * (bm + 1) / 2;
    } else if (MODE == 2) {
        bm = 63 - (int)blockIdx.x;                // longest blocks first
        bn = blockIdx.y;
    } else {
        bn = blockIdx.x; bm = blockIdx.y;
    }

    const int m0 = bm * TM;
    const int n0 = bn << 7;
    const int lda = (MODE == 2) ? 128 : DD;       // MODE2 A = packed tile rows
    const int ldb = (MODE == 2) ? SQ : DD;
    const int kst = (MODE == 1) ? (half << 9) : 0;
    const int kend = (MODE == 1) ? (kst + 512)
                   : (MODE == 2) ? (((bm >> 1) + 1) << 7) : DD;
    const bool dolo = (MODE == 1) || (MODE == 0 && bn < 16);

    __shared__ f16 sm[SMSZ];
    f16* smA  = sm;
    f16* smB  = sm + H * AH;
    f16* smAl = sm + H * (AH + BH);
    f16* smBl = smAl + H * AH;

    const int tid = threadIdx.x;
    const int w = tid >> 6, lane = tid & 63;
    const int wr = (MODE == 2) ? 0 : ((w >> 1) << 6);
    const int wc = (MODE == 2) ? (w << 5) : ((w & 1) << 6);
    const int l31 = lane & 31, khalf = lane >> 5;

    f32x16 acc[2][NI];
#pragma unroll
    for (int i = 0; i < 2; ++i)
#pragma unroll
        for (int j = 0; j < NI; ++j)
#pragma unroll
            for (int e = 0; e < 16; ++e) acc[i][j][e] = 0.f;

    const int bmT = (MODE == 2) ? (bm >> 1) : 0;
    const size_t triRow = (MODE == 2) ? (size_t)(bmT * (bmT + 1) / 2) : 0;
    const f16* Bb  = Bh + (size_t)n0 * ldb;
    const f16* Abl = dolo ? Al + (size_t)m0 * DD : nullptr;
    const f16* Bbl = dolo ? Bl + (size_t)n0 * ldb : nullptr;

    for (int k0 = kst; k0 < kend; k0 += 32 * H) {
        __syncthreads();                          // prev iter's ds_reads done
#pragma unroll
        for (int h = 0; h < H; ++h) {
            const int kk = k0 + 32 * h;
            const f16* as;
            if (MODE == 2) {
                as = Ah + ((triRow + (size_t)(kk >> 7)) << 14)
                        + ((size_t)(m0 & 127) << 7) + (kk & 127);
            } else {
                as = Ah + (size_t)m0 * DD + kk;
            }
            stage<TM / 4>(as, lda, smA + h * AH, w, lane);
            stage<32>(Bb + kk, ldb, smB + h * BH, w, lane);
            if (dolo) {
                stage<TM / 4>(Abl + kk, DD, smAl + h * AH, w, lane);
                stage<32>(Bbl + kk, ldb, smBl + h * BH, w, lane);
            }
        }
        __syncthreads();                          // vmcnt drained -> LDS valid

#pragma unroll
        for (int h = 0; h < H; ++h) {
#pragma unroll
            for (int s = 0; s < 2; ++s) {         // two K=16 steps per 32-chunk
                const int c = (s << 1) | khalf;   // logical 16B chunk
                f16x8 bh[NI], bl[NI];
#pragma unroll
                for (int in = 0; in < NI; ++in) {
                    const int rr = wc + (in << 5) + l31;
                    bh[in] = *(const f16x8*)&smB[h * BH + frag_off(rr, c)];
                    if (dolo) bl[in] = *(const f16x8*)&smBl[h * BH + frag_off(rr, c)];
                }
#pragma unroll
                for (int im = 0; im < 2; ++im) {
                    const int rr = wr + (im << 5) + l31;
                    f16x8 ah = *(const f16x8*)&smA[h * AH + frag_off(rr, c)];
                    f16x8 al;
                    if (dolo) al = *(const f16x8*)&smAl[h * AH + frag_off(rr, c)];
#pragma unroll
                    for (int in = 0; in < NI; ++in) {
                        if (dolo) {
                            acc[im][in] = __builtin_amdgcn_mfma_f32_32x32x16_f16(ah, bl[in], acc[im][in], 0, 0, 0);
                            acc[im][in] = __builtin_amdgcn_mfma_f32_32x32x16_f16(al, bh[in], acc[im][in], 0, 0, 0);
                        }
                        acc[im][in] = __builtin_amdgcn_mfma_f32_32x32x16_f16(ah, bh[in], acc[im][in], 0, 0, 0);
                    }
                }
            }
        }
    }

    // C/D: col = lane&31, row = (reg&3) + 8*(reg>>2) + 4*(lane>>5)  [m74/m101]
#pragma unroll
    for (int im = 0; im < 2; ++im) {
#pragma unroll
        for (int in = 0; in < NI; ++in) {
            if (MODE == 0) {
                const int region = bn >> 3;                       // 0=Q 1=K 2=V
                const int colL = ((bn & 7) << 7) + wc + (in << 5) + l31;
                if (region == 2) {
                    const int tcb = m0 + wr + (im << 5) + (khalf << 2);
#pragma unroll
                    for (int g = 0; g < 4; ++g) {
                        f16x4 o;
#pragma unroll
                        for (int r = 0; r < 4; ++r) o[r] = (f16)acc[im][in][(g << 2) | r];
                        *(f16x4*)&Vt[(size_t)colL * SQ + tcb + (g << 3)] = o;
                    }
                } else {
                    f16* Hh = region ? Kh : Qh;
                    f16* Hl = region ? Kl : Ql;
#pragma unroll
                    for (int e = 0; e < 16; ++e) {
                        const int row = m0 + wr + (im << 5) + (e & 3) + ((e >> 2) << 3) + (khalf << 2);
                        const float v = acc[im][in][e];
                        const f16 hh = (f16)v;
                        Hh[(size_t)row * DD + colL] = hh;
                        Hl[(size_t)row * DD + colL] = (f16)(v - (float)hh);
                    }
                }
            } else if (MODE == 1) {
                float* Cp = Cf + (((size_t)half * TRI + tri) << 14);
                const int cl = wc + (in << 5) + l31;
#pragma unroll
                for (int e = 0; e < 16; ++e) {
                    const int rl = wr + (im << 5) + (e & 3) + ((e >> 2) << 3) + (khalf << 2);
                    Cp[(rl << 7) + cl] = acc[im][in][e] * scale;
                }
            } else {
                const int col = n0 + wc + (in << 5) + l31;
#pragma unroll
                for (int e = 0; e < 16; ++e) {
                    const int row = m0 + (im << 5) + (e & 3) + ((e >> 2) << 3) + (khalf << 2);
                    Cf[(size_t)row * DD + col] = acc[im][in][e];
                }
            }
        }
    }
}

// Fused pre-pass: blocks [0,4096) split x into f16 hi/lo; blocks [4096,4864)
// transpose+split the 3 weight matrices into one [3072,1024] hi/lo pair.
__global__ __launch_bounds__(256)
void prepass(const float* __restrict__ x,
             const float* __restrict__ W0, const float* __restrict__ W1,
             const float* __restrict__ W2,
             f16* __restrict__ xh, f16* __restrict__ xl,
             f16* __restrict__ Th0, f16* __restrict__ Tl0)
{
    __shared__ float t[64][65];
    const int id = blockIdx.x;
    const int tid = threadIdx.x;

    if (id < 4096) {
        const int i = (id * 256 + tid) * 4;
        const float4 v = *(const float4*)(x + i);
        const f16 h0 = (f16)v.x, h1 = (f16)v.y, h2 = (f16)v.z, h3 = (f16)v.w;
        f16x4 hv = {h0, h1, h2, h3};
        f16x4 lv = {(f16)(v.x - (float)h0), (f16)(v.y - (float)h1),
                    (f16)(v.z - (float)h2), (f16)(v.w - (float)h3)};
        *(f16x4*)(xh + i) = hv;
        *(f16x4*)(xl + i) = lv;
        return;
    }

    const int tt = id - 4096;
    const int z = tt >> 8, r8 = tt & 255;
    const float* W = (z == 0) ? W0 : (z == 1) ? W1 : W2;
    f16* Th = Th0 + (size_t)z * DD * DD;
    f16* Tl = Tl0 + (size_t)z * DD * DD;
    const int n0 = (r8 & 15) << 6, k0 = (r8 >> 4) << 6;
    const int tx = tid & 63, ty = tid >> 6;
    for (int r = ty; r < 64; r += 4) t[r][tx] = W[(size_t)(k0 + r) * DD + n0 + tx];
    __syncthreads();
    for (int r = ty; r < 64; r += 4) {
        const float v = t[tx][r];
        const f16 h = (f16)v;
        Th[(size_t)(n0 + r) * DD + k0 + tx] = h;
        Tl[(size_t)(n0 + r) * DD + k0 + tx] = (f16)(v - (float)h);
    }
}

// Row-wise causal softmax over packed-triangular split-K partials, vectorized.
__global__ __launch_bounds__(256)
void softmax_causal(const float* __restrict__ A0, f16* __restrict__ P)
{
    const int i = blockIdx.x;
    const int n = i + 1;
    const int tid = threadIdx.x, w = tid >> 6, lane = tid & 63;
    __shared__ float redM[4], redS[4];
    __shared__ float rowbuf[SQ];                 // 16 KB merged-logit stash

    const int bmI = i >> 7;
    const size_t base = ((size_t)(bmI * (bmI + 1) / 2) << 14) + ((size_t)(i & 127) << 7);
    const float* A1 = A0 + ((size_t)TRI << 14);

    const int nv = n >> 2;                       // full float4 groups
    float m = -INFINITY;
    for (int g = tid; g < nv; g += 256) {
        const int j = g << 2;
        const size_t a = base + ((size_t)(j >> 7) << 14) + (j & 127);
        const float4 v0 = *(const float4*)(A0 + a);
        const float4 v1 = *(const float4*)(A1 + a);
        float4 v = make_float4(v0.x + v1.x, v0.y + v1.y, v0.z + v1.z, v0.w + v1.w);
        *(f32x4*)&rowbuf[j] = (f32x4){v.x, v.y, v.z, v.w};
        m = fmaxf(m, fmaxf(fmaxf(v.x, v.y), fmaxf(v.z, v.w)));
    }
    for (int j = (nv << 2) + tid; j < n; j += 256) {
        const size_t a = base + ((size_t)(j >> 7) << 14) + (j & 127);
        const float v = A0[a] + A1[a];
        rowbuf[j] = v;
        m = fmaxf(m, v);
    }
    m = waveMax(m);
    if (lane == 0) redM[w] = m;
    __syncthreads();
    const float mAll = fmaxf(fmaxf(redM[0], redM[1]), fmaxf(redM[2], redM[3]));

    float s = 0.f;
    for (int g = tid; g < nv; g += 256) {
        const int j = g << 2;
        f32x4 v = *(f32x4*)&rowbuf[j];
        v[0] = __expf(v[0] - mAll); v[1] = __expf(v[1] - mAll);
        v[2] = __expf(v[2] - mAll); v[3] = __expf(v[3] - mAll);
        *(f32x4*)&rowbuf[j] = v;
        s += v[0] + v[1] + v[2] + v[3];
    }
    for (int j = (nv << 2) + tid; j < n; j += 256) {
        const float e = __expf(rowbuf[j] - mAll);
        rowbuf[j] = e;
        s += e;
    }
    s = waveSum(s);
    if (lane == 0) redS[w] = s;
    __syncthreads();
    const float inv = 1.0f / (redS[0] + redS[1] + redS[2] + redS[3]);

    const int kmax = (bmI + 1) << 7;             // P zero-fill boundary
    for (int g = tid; g < nv; g += 256) {
        const int j = g << 2;
        const size_t a = base + ((size_t)(j >> 7) << 14) + (j & 127);
        const f32x4 v = *(const f32x4*)&rowbuf[j];
        f16x4 o = {(f16)(v[0] * inv), (f16)(v[1] * inv),
                   (f16)(v[2] * inv), (f16)(v[3] * inv)};
        *(f16x4*)&P[a] = o;
    }
    for (int j = (nv << 2) + tid; j < kmax; j += 256) {
        const size_t a = base + ((size_t)(j >> 7) << 14) + (j & 127);
        P[a] = (j < n) ? (f16)(rowbuf[j] * inv) : (f16)0.f;
    }
}

extern "C" void kernel_launch(void* const* d_in, const int* in_sizes, int n_in,
                              void* d_out, int out_size, void* d_ws, size_t ws_size,
                              hipStream_t stream)
{
    const float* x  = (const float*)d_in[0];
    const float* Wq = (const float*)d_in[1];
    const float* Wk = (const float*)d_in[2];
    const float* Wv = (const float*)d_in[3];
    float* out = (float*)d_out;

    // workspace carve (~155 MB)
    char* p = (char*)d_ws;
    auto take = [&](size_t bytes) { void* r = (void*)p; p += (bytes + 255) & ~(size_t)255; return r; };
    const size_t SD = (size_t)SQ * DD;          // 4M elems
    f16* xh  = (f16*)take(SD * 2);
    f16* xl  = (f16*)take(SD * 2);
    f16* Wth = (f16*)take((size_t)3 * DD * DD * 2);   // [3072][1024]
    f16* Wtl = (f16*)take((size_t)3 * DD * DD * 2);
    f16* Qh  = (f16*)take(SD * 2);
    f16* Ql  = (f16*)take(SD * 2);
    f16* Kh  = (f16*)take(SD * 2);
    f16* Kl  = (f16*)take(SD * 2);
    f16* Vt  = (f16*)take(SD * 2);              // [DD][SQ]
    float* attn = (float*)take((size_t)2 * TRI * 16384 * 4);  // split-K partials, packed
    f16* P   = (f16*)take((size_t)TRI * 16384 * 2);           // packed triangular

    const dim3 blk(256);

    prepass<<<dim3(4096 + 768), blk, 0, stream>>>(x, Wq, Wk, Wv, xh, xl, Wth, Wtl);

    // Merged QKV projection: 768 blocks
    gemm_k<0><<<dim3(24, SQ / 128), blk, 0, stream>>>(
        xh, xl, Wth, Wtl, nullptr, Qh, Ql, Kh, Kl, Vt, 1.0f);

    // attn partials = Q @ K^T / 32 : split-K=2, 1056 blocks, plain order
    gemm_k<1><<<dim3(2 * TRI), blk, 0, stream>>>(
        Qh, Ql, Kh, Kl, attn, nullptr, nullptr, nullptr, nullptr, nullptr, 0.03125f);

    softmax_causal<<<dim3(SQ), blk, 0, stream>>>(attn, P);

    // out = P @ V : grid (64,8), longest-first
    gemm_k<2><<<dim3(SQ / 64, DD / 128), blk, 0, stream>>>(
        P, nullptr, Vt, nullptr, out, nullptr, nullptr, nullptr, nullptr, nullptr, 1.0f);
}

// Round 10
// 296.347 us; speedup vs baseline: 1.4205x; 1.1359x over previous
//
#include <hip/hip_runtime.h>
#include <math.h>

#define SQ 4096
#define DD 1024
#define TRI 528          // causal 128x128 tiles in a 32x32 grid

typedef _Float16 f16;
typedef f16 f16x8 __attribute__((ext_vector_type(8)));
typedef f16 f16x4 __attribute__((ext_vector_type(4)));
typedef float f32x4 __attribute__((ext_vector_type(4)));

__device__ __forceinline__ float waveMax(float v) {
#pragma unroll
    for (int o = 32; o > 0; o >>= 1) v = fmaxf(v, __shfl_down(v, o, 64));
    return v;
}
__device__ __forceinline__ float waveSum(float v) {
#pragma unroll
    for (int o = 32; o > 0; o >>= 1) v += __shfl_down(v, o, 64);
    return v;
}

__device__ __forceinline__ void gl_lds16(const f16* g, f16* l) {
    __builtin_amdgcn_global_load_lds(
        (const __attribute__((address_space(1))) void*)g,
        (__attribute__((address_space(3))) void*)l, 16, 0, 0);
}

// Wave w stages NRW rows of a [*,32] f16 tile into LDS row-major [rows][32].
// Plain layout: R3 proved swizzles neutral for the 16x16 read pattern; R9's
// permutation actively regressed (write/read XOR phase mismatch at +16 rows).
template<int NRW>
__device__ __forceinline__ void stage(const f16* src, int ldk, f16* lds, int w, int lane) {
    const int r0 = w * NRW + (lane >> 2);
    const f16* g = src + (size_t)r0 * ldk + ((lane & 3) << 3);
    f16* l = lds + w * NRW * 32;
    gl_lds16(g, l);
    if (NRW == 32) gl_lds16(g + (size_t)ldk * 16, l + 16 * 32);
}

// Unified TN GEMM over K-contiguous f16 operands, 16x16x32 MFMA (proven best).
// MODE 0: merged QKV projection, 128x128, BK=32, grid (24,32)=768 blocks (3/CU).
//         bn<16 (Q,K): split3 + hi/lo split-store. bn>=16 (V): hi-only +
//         transposed f16 store.
// MODE 1: QK^T split-K=2, packed-triangular f32 partials, BK=32, 1-D grid 1056
//         in PLAIN order (R7's XCD swizzle raised FETCH 86->106 MB; reverted).
// MODE 2: PV. A=P packed-triangular, B=Vt [DD,SQ], hi-only, 64x128, BK=64,
//         kend=(bmT+1)*128. grid (64,8), bm reversed = longest blocks first.
template<int MODE>
__global__ __launch_bounds__(256)
void gemm_k(const f16* __restrict__ Ah, const f16* __restrict__ Al,
            const f16* __restrict__ Bh, const f16* __restrict__ Bl,
            float* __restrict__ Cf,
            f16* __restrict__ Qh, f16* __restrict__ Ql,
            f16* __restrict__ Kh, f16* __restrict__ Kl,
            f16* __restrict__ Vt, float scale)
{
    constexpr int TM = (MODE == 2) ? 64 : 128;
    constexpr int NI = (MODE == 2) ? 2 : 4;       // 16-col frags per wave
    constexpr int H  = (MODE == 2) ? 2 : 1;       // BK/32 half-tiles
    constexpr int AH = TM * 32;                   // f16 per A half-tile
    constexpr int BH = 128 * 32;
    constexpr int SMSZ = (MODE == 2) ? H * (AH + BH) : 2 * H * (AH + BH);

    int bm, bn, tri = 0, half = 0;
    if (MODE == 1) {
        const int lin = blockIdx.x;               // plain order
        half = lin & 1;
        tri = lin >> 1;
        bm = (int)((sqrtf(8.f * (float)tri + 1.f) - 1.f) * 0.5f);
        while ((bm + 1) * (bm + 2) / 2 <= tri) ++bm;
        while (bm * (bm + 1) / 2 > tri) --bm;
        bn = tri - bm * (bm + 1) / 2;
    } else if (MODE == 2) {
        bm = 63 - (int)blockIdx.x;                // longest blocks first
        bn = blockIdx.y;
    } else {
        bn = blockIdx.x; bm = blockIdx.y;
    }

    const int m0 = bm * TM;
    const int n0 = bn << 7;
    const int lda = (MODE == 2) ? 128 : DD;       // MODE2 A = packed tile rows
    const int ldb = (MODE == 2) ? SQ : DD;
    const int kst = (MODE == 1) ? (half << 9) : 0;
    const int kend = (MODE == 1) ? (kst + 512)
                   : (MODE == 2) ? (((bm >> 1) + 1) << 7) : DD;
    const bool dolo = (MODE == 1) || (MODE == 0 && bn < 16);

    __shared__ f16 sm[SMSZ];
    f16* smA  = sm;
    f16* smB  = sm + H * AH;
    f16* smAl = sm + H * (AH + BH);
    f16* smBl = smAl + H * AH;

    const int tid = threadIdx.x;
    const int w = tid >> 6, lane = tid & 63;
    const int wr = (MODE == 2) ? 0 : ((w >> 1) << 6);
    const int wc = (MODE == 2) ? (w << 5) : ((w & 1) << 6);
    const int fcol = lane & 15, quad = lane >> 4;

    f32x4 acc[4][NI];
#pragma unroll
    for (int i = 0; i < 4; ++i)
#pragma unroll
        for (int j = 0; j < NI; ++j) acc[i][j] = (f32x4){0.f, 0.f, 0.f, 0.f};

    const int bmT = (MODE == 2) ? (bm >> 1) : 0;
    const size_t triRow = (MODE == 2) ? (size_t)(bmT * (bmT + 1) / 2) : 0;
    const f16* Bb  = Bh + (size_t)n0 * ldb;
    const f16* Abl = dolo ? Al + (size_t)m0 * DD : nullptr;
    const f16* Bbl = dolo ? Bl + (size_t)n0 * ldb : nullptr;

    for (int k0 = kst; k0 < kend; k0 += 32 * H) {
        __syncthreads();                          // prev iter's ds_reads done
#pragma unroll
        for (int h = 0; h < H; ++h) {
            const int kk = k0 + 32 * h;
            const f16* as;
            if (MODE == 2) {
                as = Ah + ((triRow + (size_t)(kk >> 7)) << 14)
                        + ((size_t)(m0 & 127) << 7) + (kk & 127);
            } else {
                as = Ah + (size_t)m0 * DD + kk;
            }
            stage<TM / 4>(as, lda, smA + h * AH, w, lane);
            stage<32>(Bb + kk, ldb, smB + h * BH, w, lane);
            if (dolo) {
                stage<TM / 4>(Abl + kk, DD, smAl + h * AH, w, lane);
                stage<32>(Bbl + kk, ldb, smBl + h * BH, w, lane);
            }
        }
        __syncthreads();                          // vmcnt drained -> LDS valid

#pragma unroll
        for (int h = 0; h < H; ++h) {
            f16x8 bh[NI], bl[NI];
#pragma unroll
            for (int in = 0; in < NI; ++in) {
                const int off = ((wc + (in << 4) + fcol) << 5) + (quad << 3);
                bh[in] = *(const f16x8*)&smB[h * BH + off];
                if (dolo) bl[in] = *(const f16x8*)&smBl[h * BH + off];
            }
#pragma unroll
            for (int im = 0; im < 4; ++im) {
                const int off = ((wr + (im << 4) + fcol) << 5) + (quad << 3);
                f16x8 ah = *(const f16x8*)&smA[h * AH + off];
                f16x8 al;
                if (dolo) al = *(const f16x8*)&smAl[h * AH + off];
#pragma unroll
                for (int in = 0; in < NI; ++in) {
                    if (dolo) {
                        acc[im][in] = __builtin_amdgcn_mfma_f32_16x16x32_f16(ah, bl[in], acc[im][in], 0, 0, 0);
                        acc[im][in] = __builtin_amdgcn_mfma_f32_16x16x32_f16(al, bh[in], acc[im][in], 0, 0, 0);
                    }
                    acc[im][in] = __builtin_amdgcn_mfma_f32_16x16x32_f16(ah, bh[in], acc[im][in], 0, 0, 0);
                }
            }
        }
    }

    // C/D layout: col = lane&15, row = quad*4 + r  [m89-verified]
#pragma unroll
    for (int im = 0; im < 4; ++im) {
#pragma unroll
        for (int in = 0; in < NI; ++in) {
            if (MODE == 0) {
                const int region = bn >> 3;                       // 0=Q 1=K 2=V
                const int colL = ((bn & 7) << 7) + wc + (in << 4) + fcol;
                if (region == 2) {
                    const int tc = m0 + wr + (im << 4) + (quad << 2);
                    f16x4 o;
#pragma unroll
                    for (int r = 0; r < 4; ++r) o[r] = (f16)acc[im][in][r];
                    *(f16x4*)&Vt[(size_t)colL * SQ + tc] = o;
                } else {
                    f16* Hh = region ? Kh : Qh;
                    f16* Hl = region ? Kl : Ql;
#pragma unroll
                    for (int r = 0; r < 4; ++r) {
                        const int row = m0 + wr + (im << 4) + (quad << 2) + r;
                        const float v = acc[im][in][r];
                        const f16 h = (f16)v;
                        Hh[(size_t)row * DD + colL] = h;
                        Hl[(size_t)row * DD + colL] = (f16)(v - (float)h);
                    }
                }
            } else if (MODE == 1) {
                float* Cp = Cf + (((size_t)half * TRI + tri) << 14);
#pragma unroll
                for (int r = 0; r < 4; ++r) {
                    const int rl = wr + (im << 4) + (quad << 2) + r;
                    const int cl = wc + (in << 4) + fcol;
                    Cp[(rl << 7) + cl] = acc[im][in][r] * scale;
                }
            } else {
#pragma unroll
                for (int r = 0; r < 4; ++r) {
                    const int row = m0 + wr + (im << 4) + (quad << 2) + r;
                    const int col = n0 + wc + (in << 4) + fcol;
                    Cf[(size_t)row * DD + col] = acc[im][in][r];
                }
            }
        }
    }
}

// Fused pre-pass: blocks [0,4096) split x into f16 hi/lo; blocks [4096,4864)
// transpose+split the 3 weight matrices into one [3072,1024] hi/lo pair.
__global__ __launch_bounds__(256)
void prepass(const float* __restrict__ x,
             const float* __restrict__ W0, const float* __restrict__ W1,
             const float* __restrict__ W2,
             f16* __restrict__ xh, f16* __restrict__ xl,
             f16* __restrict__ Th0, f16* __restrict__ Tl0)
{
    __shared__ float t[64][65];
    const int id = blockIdx.x;
    const int tid = threadIdx.x;

    if (id < 4096) {
        const int i = (id * 256 + tid) * 4;
        const float4 v = *(const float4*)(x + i);
        const f16 h0 = (f16)v.x, h1 = (f16)v.y, h2 = (f16)v.z, h3 = (f16)v.w;
        f16x4 hv = {h0, h1, h2, h3};
        f16x4 lv = {(f16)(v.x - (float)h0), (f16)(v.y - (float)h1),
                    (f16)(v.z - (float)h2), (f16)(v.w - (float)h3)};
        *(f16x4*)(xh + i) = hv;
        *(f16x4*)(xl + i) = lv;
        return;
    }

    const int tt = id - 4096;
    const int z = tt >> 8, r8 = tt & 255;
    const float* W = (z == 0) ? W0 : (z == 1) ? W1 : W2;
    f16* Th = Th0 + (size_t)z * DD * DD;
    f16* Tl = Tl0 + (size_t)z * DD * DD;
    const int n0 = (r8 & 15) << 6, k0 = (r8 >> 4) << 6;
    const int tx = tid & 63, ty = tid >> 6;
    for (int r = ty; r < 64; r += 4) t[r][tx] = W[(size_t)(k0 + r) * DD + n0 + tx];
    __syncthreads();
    for (int r = ty; r < 64; r += 4) {
        const float v = t[tx][r];
        const f16 h = (f16)v;
        Th[(size_t)(n0 + r) * DD + k0 + tx] = h;
        Tl[(size_t)(n0 + r) * DD + k0 + tx] = (f16)(v - (float)h);
    }
}

// Row-wise causal softmax over packed-triangular split-K partials, vectorized:
// float4 loads of both partials, f16x4 P stores (packed layout keeps j
// contiguous within each 128-tile).
__global__ __launch_bounds__(256)
void softmax_causal(const float* __restrict__ A0, f16* __restrict__ P)
{
    const int i = blockIdx.x;
    const int n = i + 1;
    const int tid = threadIdx.x, w = tid >> 6, lane = tid & 63;
    __shared__ float redM[4], redS[4];
    __shared__ float rowbuf[SQ];                 // 16 KB merged-logit stash

    const int bmI = i >> 7;
    const size_t base = ((size_t)(bmI * (bmI + 1) / 2) << 14) + ((size_t)(i & 127) << 7);
    const float* A1 = A0 + ((size_t)TRI << 14);

    const int nv = n >> 2;                       // full float4 groups
    float m = -INFINITY;
    for (int g = tid; g < nv; g += 256) {
        const int j = g << 2;
        const size_t a = base + ((size_t)(j >> 7) << 14) + (j & 127);
        const float4 v0 = *(const float4*)(A0 + a);
        const float4 v1 = *(const float4*)(A1 + a);
        float4 v = make_float4(v0.x + v1.x, v0.y + v1.y, v0.z + v1.z, v0.w + v1.w);
        *(f32x4*)&rowbuf[j] = (f32x4){v.x, v.y, v.z, v.w};
        m = fmaxf(m, fmaxf(fmaxf(v.x, v.y), fmaxf(v.z, v.w)));
    }
    for (int j = (nv << 2) + tid; j < n; j += 256) {
        const size_t a = base + ((size_t)(j >> 7) << 14) + (j & 127);
        const float v = A0[a] + A1[a];
        rowbuf[j] = v;
        m = fmaxf(m, v);
    }
    m = waveMax(m);
    if (lane == 0) redM[w] = m;
    __syncthreads();
    const float mAll = fmaxf(fmaxf(redM[0], redM[1]), fmaxf(redM[2], redM[3]));

    float s = 0.f;
    for (int g = tid; g < nv; g += 256) {
        const int j = g << 2;
        f32x4 v = *(f32x4*)&rowbuf[j];
        v[0] = __expf(v[0] - mAll); v[1] = __expf(v[1] - mAll);
        v[2] = __expf(v[2] - mAll); v[3] = __expf(v[3] - mAll);
        *(f32x4*)&rowbuf[j] = v;
        s += v[0] + v[1] + v[2] + v[3];
    }
    for (int j = (nv << 2) + tid; j < n; j += 256) {
        const float e = __expf(rowbuf[j] - mAll);
        rowbuf[j] = e;
        s += e;
    }
    s = waveSum(s);
    if (lane == 0) redS[w] = s;
    __syncthreads();
    const float inv = 1.0f / (redS[0] + redS[1] + redS[2] + redS[3]);

    const int kmax = (bmI + 1) << 7;             // P zero-fill boundary
    for (int g = tid; g < nv; g += 256) {
        const int j = g << 2;
        const size_t a = base + ((size_t)(j >> 7) << 14) + (j & 127);
        const f32x4 v = *(const f32x4*)&rowbuf[j];
        f16x4 o = {(f16)(v[0] * inv), (f16)(v[1] * inv),
                   (f16)(v[2] * inv), (f16)(v[3] * inv)};
        *(f16x4*)&P[a] = o;
    }
    for (int j = (nv << 2) + tid; j < kmax; j += 256) {
        const size_t a = base + ((size_t)(j >> 7) << 14) + (j & 127);
        P[a] = (j < n) ? (f16)(rowbuf[j] * inv) : (f16)0.f;
    }
}

extern "C" void kernel_launch(void* const* d_in, const int* in_sizes, int n_in,
                              void* d_out, int out_size, void* d_ws, size_t ws_size,
                              hipStream_t stream)
{
    const float* x  = (const float*)d_in[0];
    const float* Wq = (const float*)d_in[1];
    const float* Wk = (const float*)d_in[2];
    const float* Wv = (const float*)d_in[3];
    float* out = (float*)d_out;

    // workspace carve (~155 MB)
    char* p = (char*)d_ws;
    auto take = [&](size_t bytes) { void* r = (void*)p; p += (bytes + 255) & ~(size_t)255; return r; };
    const size_t SD = (size_t)SQ * DD;          // 4M elems
    f16* xh  = (f16*)take(SD * 2);
    f16* xl  = (f16*)take(SD * 2);
    f16* Wth = (f16*)take((size_t)3 * DD * DD * 2);   // [3072][1024]
    f16* Wtl = (f16*)take((size_t)3 * DD * DD * 2);
    f16* Qh  = (f16*)take(SD * 2);
    f16* Ql  = (f16*)take(SD * 2);
    f16* Kh  = (f16*)take(SD * 2);
    f16* Kl  = (f16*)take(SD * 2);
    f16* Vt  = (f16*)take(SD * 2);              // [DD][SQ]
    float* attn = (float*)take((size_t)2 * TRI * 16384 * 4);  // split-K partials, packed
    f16* P   = (f16*)take((size_t)TRI * 16384 * 2);           // packed triangular

    const dim3 blk(256);

    prepass<<<dim3(4096 + 768), blk, 0, stream>>>(x, Wq, Wk, Wv, xh, xl, Wth, Wtl);

    // Merged QKV projection: 768 blocks, BK=32
    gemm_k<0><<<dim3(24, SQ / 128), blk, 0, stream>>>(
        xh, xl, Wth, Wtl, nullptr, Qh, Ql, Kh, Kl, Vt, 1.0f);

    // attn partials = Q @ K^T / 32 : split-K=2, 1056 blocks, plain order
    gemm_k<1><<<dim3(2 * TRI), blk, 0, stream>>>(
        Qh, Ql, Kh, Kl, attn, nullptr, nullptr, nullptr, nullptr, nullptr, 0.03125f);

    softmax_causal<<<dim3(SQ), blk, 0, stream>>>(attn, P);

    // out = P @ V : grid (64,8), longest-first
    gemm_k<2><<<dim3(SQ / 64, DD / 128), blk, 0, stream>>>(
        P, nullptr, Vt, nullptr, out, nullptr, nullptr, nullptr, nullptr, nullptr, 1.0f);
}

// Round 11
// 289.058 us; speedup vs baseline: 1.4563x; 1.0252x over previous
//
#include <hip/hip_runtime.h>
#include <math.h>

#define SQ 4096
#define DD 1024
#define TRI 528          // causal 128x128 tiles in a 32x32 grid

typedef _Float16 f16;
typedef f16 f16x8 __attribute__((ext_vector_type(8)));
typedef f16 f16x4 __attribute__((ext_vector_type(4)));
typedef float f32x4 __attribute__((ext_vector_type(4)));

__device__ __forceinline__ float waveMax(float v) {
#pragma unroll
    for (int o = 32; o > 0; o >>= 1) v = fmaxf(v, __shfl_down(v, o, 64));
    return v;
}
__device__ __forceinline__ float waveSum(float v) {
#pragma unroll
    for (int o = 32; o > 0; o >>= 1) v += __shfl_down(v, o, 64);
    return v;
}

__device__ __forceinline__ void gl_lds16(const f16* g, f16* l) {
    __builtin_amdgcn_global_load_lds(
        (const __attribute__((address_space(1))) void*)g,
        (__attribute__((address_space(3))) void*)l, 16, 0, 0);
}

// Wave w stages NRW rows of a [*,32] f16 tile into LDS row-major [rows][32].
// Plain layout (R3: swizzles neutral for 16x16 reads; R9 permutation regressed).
template<int NRW>
__device__ __forceinline__ void stage(const f16* src, int ldk, f16* lds, int w, int lane) {
    const int r0 = w * NRW + (lane >> 2);
    const f16* g = src + (size_t)r0 * ldk + ((lane & 3) << 3);
    f16* l = lds + w * NRW * 32;
    gl_lds16(g, l);
    if (NRW == 32) gl_lds16(g + (size_t)ldk * 16, l + 16 * 32);
}

// Unified TN GEMM over K-contiguous f16 operands, 16x16x32 MFMA (proven best).
// Numerics (error budget vs 1.92 absmax threshold):
//  - x-side split is MANDATORY for Q/K: delta-x is shared across output cols and
//    amplifies coherently into logits (~4 scaled if dropped).
//  - W-side split is UNNECESSARY: delta-W is iid across (k,d), contributes
//    ~0.02 scaled to logits. -> proj Q/K = 2 MFMAs (xh*W + xl*W), W plain f16.
//  - QK^T keeps full split3 (dropping cross terms would add ~0.2 scaled: risky).
// MODE 0: merged QKV projection, 128x128, BK=32, grid (24,32)=768 blocks (3/CU).
//         bn<16 (Q,K): x-split 2-MFMA + hi/lo split-store. bn>=16 (V): hi-only
//         1-MFMA + transposed f16 store. LDS 24 KB (Ah,Al,Bh).
// MODE 1: QK^T split-K=2, split3, packed-triangular f32 partials, BK=32,
//         1-D grid 1056 plain order. LDS 32 KB.
// MODE 2: PV. A=P packed-triangular, B=Vt [DD,SQ], hi-only, 64x128, BK=64,
//         kend=(bmT+1)*128. grid (64,8), bm reversed = longest first. LDS 24 KB.
template<int MODE>
__global__ __launch_bounds__(256)
void gemm_k(const f16* __restrict__ Ah, const f16* __restrict__ Al,
            const f16* __restrict__ Bh, const f16* __restrict__ Bl,
            float* __restrict__ Cf,
            f16* __restrict__ Qh, f16* __restrict__ Ql,
            f16* __restrict__ Kh, f16* __restrict__ Kl,
            f16* __restrict__ Vt, float scale)
{
    constexpr int TM = (MODE == 2) ? 64 : 128;
    constexpr int NI = (MODE == 2) ? 2 : 4;       // 16-col frags per wave
    constexpr int H  = (MODE == 2) ? 2 : 1;       // BK/32 half-tiles
    constexpr int AH = TM * 32;                   // f16 per A half-tile
    constexpr int BH = 128 * 32;
    constexpr bool HAS_AL = (MODE != 2);          // A-lo tile may be staged
    constexpr bool HAS_BL = (MODE == 1);          // B-lo tile staged (split3 only)
    constexpr int SMSZ = H * AH + H * BH + (HAS_AL ? H * AH : 0) + (HAS_BL ? H * BH : 0);

    int bm, bn, tri = 0, half = 0;
    if (MODE == 1) {
        const int lin = blockIdx.x;               // plain order
        half = lin & 1;
        tri = lin >> 1;
        bm = (int)((sqrtf(8.f * (float)tri + 1.f) - 1.f) * 0.5f);
        while ((bm + 1) * (bm + 2) / 2 <= tri) ++bm;
        while (bm * (bm + 1) / 2 > tri) --bm;
        bn = tri - bm * (bm + 1) / 2;
    } else if (MODE == 2) {
        bm = 63 - (int)blockIdx.x;                // longest blocks first
        bn = blockIdx.y;
    } else {
        bn = blockIdx.x; bm = blockIdx.y;
    }

    const int m0 = bm * TM;
    const int n0 = bn << 7;
    const int lda = (MODE == 2) ? 128 : DD;       // MODE2 A = packed tile rows
    const int ldb = (MODE == 2) ? SQ : DD;
    const int kst = (MODE == 1) ? (half << 9) : 0;
    const int kend = (MODE == 1) ? (kst + 512)
                   : (MODE == 2) ? (((bm >> 1) + 1) << 7) : DD;
    // does this block use the A-lo term?
    const bool aLo = (MODE == 1) || (MODE == 0 && bn < 16);

    __shared__ f16 sm[SMSZ];
    f16* smA  = sm;
    f16* smB  = sm + H * AH;
    f16* smAl = smB + H * BH;                     // valid iff HAS_AL
    f16* smBl = smAl + (HAS_AL ? H * AH : 0);     // valid iff HAS_BL

    const int tid = threadIdx.x;
    const int w = tid >> 6, lane = tid & 63;
    const int wr = (MODE == 2) ? 0 : ((w >> 1) << 6);
    const int wc = (MODE == 2) ? (w << 5) : ((w & 1) << 6);
    const int fcol = lane & 15, quad = lane >> 4;

    f32x4 acc[4][NI];
#pragma unroll
    for (int i = 0; i < 4; ++i)
#pragma unroll
        for (int j = 0; j < NI; ++j) acc[i][j] = (f32x4){0.f, 0.f, 0.f, 0.f};

    const int bmT = (MODE == 2) ? (bm >> 1) : 0;
    const size_t triRow = (MODE == 2) ? (size_t)(bmT * (bmT + 1) / 2) : 0;
    const f16* Bb  = Bh + (size_t)n0 * ldb;
    const f16* Abl = (HAS_AL && aLo) ? Al + (size_t)m0 * DD : nullptr;
    const f16* Bbl = HAS_BL ? Bl + (size_t)n0 * ldb : nullptr;

    for (int k0 = kst; k0 < kend; k0 += 32 * H) {
        __syncthreads();                          // prev iter's ds_reads done
#pragma unroll
        for (int h = 0; h < H; ++h) {
            const int kk = k0 + 32 * h;
            const f16* as;
            if (MODE == 2) {
                as = Ah + ((triRow + (size_t)(kk >> 7)) << 14)
                        + ((size_t)(m0 & 127) << 7) + (kk & 127);
            } else {
                as = Ah + (size_t)m0 * DD + kk;
            }
            stage<TM / 4>(as, lda, smA + h * AH, w, lane);
            stage<32>(Bb + kk, ldb, smB + h * BH, w, lane);
            if (HAS_AL && aLo) stage<TM / 4>(Abl + kk, DD, smAl + h * AH, w, lane);
            if (HAS_BL)        stage<32>(Bbl + kk, ldb, smBl + h * BH, w, lane);
        }
        __syncthreads();                          // vmcnt drained -> LDS valid

#pragma unroll
        for (int h = 0; h < H; ++h) {
            f16x8 bh[NI], bl[NI];
#pragma unroll
            for (int in = 0; in < NI; ++in) {
                const int off = ((wc + (in << 4) + fcol) << 5) + (quad << 3);
                bh[in] = *(const f16x8*)&smB[h * BH + off];
                if (HAS_BL) bl[in] = *(const f16x8*)&smBl[h * BH + off];
            }
#pragma unroll
            for (int im = 0; im < 4; ++im) {
                const int off = ((wr + (im << 4) + fcol) << 5) + (quad << 3);
                f16x8 ah = *(const f16x8*)&smA[h * AH + off];
                f16x8 al;
                if (HAS_AL && aLo) al = *(const f16x8*)&smAl[h * AH + off];
#pragma unroll
                for (int in = 0; in < NI; ++in) {
                    if (HAS_BL)
                        acc[im][in] = __builtin_amdgcn_mfma_f32_16x16x32_f16(ah, bl[in], acc[im][in], 0, 0, 0);
                    if (HAS_AL && aLo)
                        acc[im][in] = __builtin_amdgcn_mfma_f32_16x16x32_f16(al, bh[in], acc[im][in], 0, 0, 0);
                    acc[im][in] = __builtin_amdgcn_mfma_f32_16x16x32_f16(ah, bh[in], acc[im][in], 0, 0, 0);
                }
            }
        }
    }

    // C/D layout: col = lane&15, row = quad*4 + r  [m89-verified]
#pragma unroll
    for (int im = 0; im < 4; ++im) {
#pragma unroll
        for (int in = 0; in < NI; ++in) {
            if (MODE == 0) {
                const int region = bn >> 3;                       // 0=Q 1=K 2=V
                const int colL = ((bn & 7) << 7) + wc + (in << 4) + fcol;
                if (region == 2) {
                    const int tc = m0 + wr + (im << 4) + (quad << 2);
                    f16x4 o;
#pragma unroll
                    for (int r = 0; r < 4; ++r) o[r] = (f16)acc[im][in][r];
                    *(f16x4*)&Vt[(size_t)colL * SQ + tc] = o;
                } else {
                    f16* Hh = region ? Kh : Qh;
                    f16* Hl = region ? Kl : Ql;
#pragma unroll
                    for (int r = 0; r < 4; ++r) {
                        const int row = m0 + wr + (im << 4) + (quad << 2) + r;
                        const float v = acc[im][in][r];
                        const f16 h = (f16)v;
                        Hh[(size_t)row * DD + colL] = h;
                        Hl[(size_t)row * DD + colL] = (f16)(v - (float)h);
                    }
                }
            } else if (MODE == 1) {
                float* Cp = Cf + (((size_t)half * TRI + tri) << 14);
#pragma unroll
                for (int r = 0; r < 4; ++r) {
                    const int rl = wr + (im << 4) + (quad << 2) + r;
                    const int cl = wc + (in << 4) + fcol;
                    Cp[(rl << 7) + cl] = acc[im][in][r] * scale;
                }
            } else {
#pragma unroll
                for (int r = 0; r < 4; ++r) {
                    const int row = m0 + wr + (im << 4) + (quad << 2) + r;
                    const int col = n0 + wc + (in << 4) + fcol;
                    Cf[(size_t)row * DD + col] = acc[im][in][r];
                }
            }
        }
    }
}

// Fused pre-pass: blocks [0,4096) split x into f16 hi/lo; blocks [4096,4864)
// transpose the 3 weight matrices into one [3072,1024] f16 buffer (hi only —
// W-side lo proven unnecessary by the iid-rounding analysis).
__global__ __launch_bounds__(256)
void prepass(const float* __restrict__ x,
             const float* __restrict__ W0, const float* __restrict__ W1,
             const float* __restrict__ W2,
             f16* __restrict__ xh, f16* __restrict__ xl,
             f16* __restrict__ Th0)
{
    __shared__ float t[64][65];
    const int id = blockIdx.x;
    const int tid = threadIdx.x;

    if (id < 4096) {
        const int i = (id * 256 + tid) * 4;
        const float4 v = *(const float4*)(x + i);
        const f16 h0 = (f16)v.x, h1 = (f16)v.y, h2 = (f16)v.z, h3 = (f16)v.w;
        f16x4 hv = {h0, h1, h2, h3};
        f16x4 lv = {(f16)(v.x - (float)h0), (f16)(v.y - (float)h1),
                    (f16)(v.z - (float)h2), (f16)(v.w - (float)h3)};
        *(f16x4*)(xh + i) = hv;
        *(f16x4*)(xl + i) = lv;
        return;
    }

    const int tt = id - 4096;
    const int z = tt >> 8, r8 = tt & 255;
    const float* W = (z == 0) ? W0 : (z == 1) ? W1 : W2;
    f16* Th = Th0 + (size_t)z * DD * DD;
    const int n0 = (r8 & 15) << 6, k0 = (r8 >> 4) << 6;
    const int tx = tid & 63, ty = tid >> 6;
    for (int r = ty; r < 64; r += 4) t[r][tx] = W[(size_t)(k0 + r) * DD + n0 + tx];
    __syncthreads();
    for (int r = ty; r < 64; r += 4)
        Th[(size_t)(n0 + r) * DD + k0 + tx] = (f16)t[tx][r];
}

// Row-wise causal softmax over packed-triangular split-K partials, vectorized:
// float4 loads of both partials, f16x4 P stores (packed layout keeps j
// contiguous within each 128-tile).
__global__ __launch_bounds__(256)
void softmax_causal(const float* __restrict__ A0, f16* __restrict__ P)
{
    const int i = blockIdx.x;
    const int n = i + 1;
    const int tid = threadIdx.x, w = tid >> 6, lane = tid & 63;
    __shared__ float redM[4], redS[4];
    __shared__ float rowbuf[SQ];                 // 16 KB merged-logit stash

    const int bmI = i >> 7;
    const size_t base = ((size_t)(bmI * (bmI + 1) / 2) << 14) + ((size_t)(i & 127) << 7);
    const float* A1 = A0 + ((size_t)TRI << 14);

    const int nv = n >> 2;                       // full float4 groups
    float m = -INFINITY;
    for (int g = tid; g < nv; g += 256) {
        const int j = g << 2;
        const size_t a = base + ((size_t)(j >> 7) << 14) + (j & 127);
        const float4 v0 = *(const float4*)(A0 + a);
        const float4 v1 = *(const float4*)(A1 + a);
        float4 v = make_float4(v0.x + v1.x, v0.y + v1.y, v0.z + v1.z, v0.w + v1.w);
        *(f32x4*)&rowbuf[j] = (f32x4){v.x, v.y, v.z, v.w};
        m = fmaxf(m, fmaxf(fmaxf(v.x, v.y), fmaxf(v.z, v.w)));
    }
    for (int j = (nv << 2) + tid; j < n; j += 256) {
        const size_t a = base + ((size_t)(j >> 7) << 14) + (j & 127);
        const float v = A0[a] + A1[a];
        rowbuf[j] = v;
        m = fmaxf(m, v);
    }
    m = waveMax(m);
    if (lane == 0) redM[w] = m;
    __syncthreads();
    const float mAll = fmaxf(fmaxf(redM[0], redM[1]), fmaxf(redM[2], redM[3]));

    float s = 0.f;
    for (int g = tid; g < nv; g += 256) {
        const int j = g << 2;
        f32x4 v = *(f32x4*)&rowbuf[j];
        v[0] = __expf(v[0] - mAll); v[1] = __expf(v[1] - mAll);
        v[2] = __expf(v[2] - mAll); v[3] = __expf(v[3] - mAll);
        *(f32x4*)&rowbuf[j] = v;
        s += v[0] + v[1] + v[2] + v[3];
    }
    for (int j = (nv << 2) + tid; j < n; j += 256) {
        const float e = __expf(rowbuf[j] - mAll);
        rowbuf[j] = e;
        s += e;
    }
    s = waveSum(s);
    if (lane == 0) redS[w] = s;
    __syncthreads();
    const float inv = 1.0f / (redS[0] + redS[1] + redS[2] + redS[3]);

    const int kmax = (bmI + 1) << 7;             // P zero-fill boundary
    for (int g = tid; g < nv; g += 256) {
        const int j = g << 2;
        const size_t a = base + ((size_t)(j >> 7) << 14) + (j & 127);
        const f32x4 v = *(const f32x4*)&rowbuf[j];
        f16x4 o = {(f16)(v[0] * inv), (f16)(v[1] * inv),
                   (f16)(v[2] * inv), (f16)(v[3] * inv)};
        *(f16x4*)&P[a] = o;
    }
    for (int j = (nv << 2) + tid; j < kmax; j += 256) {
        const size_t a = base + ((size_t)(j >> 7) << 14) + (j & 127);
        P[a] = (j < n) ? (f16)(rowbuf[j] * inv) : (f16)0.f;
    }
}

extern "C" void kernel_launch(void* const* d_in, const int* in_sizes, int n_in,
                              void* d_out, int out_size, void* d_ws, size_t ws_size,
                              hipStream_t stream)
{
    const float* x  = (const float*)d_in[0];
    const float* Wq = (const float*)d_in[1];
    const float* Wk = (const float*)d_in[2];
    const float* Wv = (const float*)d_in[3];
    float* out = (float*)d_out;

    // workspace carve (~149 MB)
    char* p = (char*)d_ws;
    auto take = [&](size_t bytes) { void* r = (void*)p; p += (bytes + 255) & ~(size_t)255; return r; };
    const size_t SD = (size_t)SQ * DD;          // 4M elems
    f16* xh  = (f16*)take(SD * 2);
    f16* xl  = (f16*)take(SD * 2);
    f16* Wth = (f16*)take((size_t)3 * DD * DD * 2);   // [3072][1024], hi only
    f16* Qh  = (f16*)take(SD * 2);
    f16* Ql  = (f16*)take(SD * 2);
    f16* Kh  = (f16*)take(SD * 2);
    f16* Kl  = (f16*)take(SD * 2);
    f16* Vt  = (f16*)take(SD * 2);              // [DD][SQ]
    float* attn = (float*)take((size_t)2 * TRI * 16384 * 4);  // split-K partials, packed
    f16* P   = (f16*)take((size_t)TRI * 16384 * 2);           // packed triangular

    const dim3 blk(256);

    prepass<<<dim3(4096 + 768), blk, 0, stream>>>(x, Wq, Wk, Wv, xh, xl, Wth);

    // Merged QKV projection: 768 blocks, BK=32, x-split 2-MFMA (W plain f16)
    gemm_k<0><<<dim3(24, SQ / 128), blk, 0, stream>>>(
        xh, xl, Wth, nullptr, nullptr, Qh, Ql, Kh, Kl, Vt, 1.0f);

    // attn partials = Q @ K^T / 32 : split-K=2, split3, 1056 blocks, plain order
    gemm_k<1><<<dim3(2 * TRI), blk, 0, stream>>>(
        Qh, Ql, Kh, Kl, attn, nullptr, nullptr, nullptr, nullptr, nullptr, 0.03125f);

    softmax_causal<<<dim3(SQ), blk, 0, stream>>>(attn, P);

    // out = P @ V : grid (64,8), longest-first
    gemm_k<2><<<dim3(SQ / 64, DD / 128), blk, 0, stream>>>(
        P, nullptr, Vt, nullptr, out, nullptr, nullptr, nullptr, nullptr, nullptr, 1.0f);
}

// Round 12
// 272.206 us; speedup vs baseline: 1.5464x; 1.0619x over previous
//
#include <hip/hip_runtime.h>
#include <math.h>

#define SQ 4096
#define DD 1024
#define TRI 528          // causal 128x128 tiles in a 32x32 grid

typedef _Float16 f16;
typedef f16 f16x8 __attribute__((ext_vector_type(8)));
typedef f16 f16x4 __attribute__((ext_vector_type(4)));
typedef float f32x4 __attribute__((ext_vector_type(4)));

__device__ __forceinline__ float waveMax(float v) {
#pragma unroll
    for (int o = 32; o > 0; o >>= 1) v = fmaxf(v, __shfl_down(v, o, 64));
    return v;
}
__device__ __forceinline__ float waveSum(float v) {
#pragma unroll
    for (int o = 32; o > 0; o >>= 1) v += __shfl_down(v, o, 64);
    return v;
}

__device__ __forceinline__ void gl_lds16(const f16* g, f16* l) {
    __builtin_amdgcn_global_load_lds(
        (const __attribute__((address_space(1))) void*)g,
        (__attribute__((address_space(3))) void*)l, 16, 0, 0);
}

// Wave w stages NRW rows of a [*,32] f16 tile into LDS row-major [rows][32].
// Plain layout (R3: swizzles neutral for 16x16 reads; R9 permutation regressed).
template<int NRW>
__device__ __forceinline__ void stage(const f16* src, int ldk, f16* lds, int w, int lane) {
    const int r0 = w * NRW + (lane >> 2);
    const f16* g = src + (size_t)r0 * ldk + ((lane & 3) << 3);
    f16* l = lds + w * NRW * 32;
#pragma unroll
    for (int i = 0; i < NRW / 16; ++i)
        gl_lds16(g + (size_t)ldk * (i << 4), l + (i << 4) * 32);
}

// Unified TN GEMM over K-contiguous f16 operands, 16x16x32 MFMA (proven best).
// Numerics (frozen as of R11): x-side split mandatory for Q/K (coherent error),
// W-side split unnecessary (iid error ~0.02 scaled), QK^T full split3.
// MODE 0: merged QKV projection, 128x128, BK=32, grid (24,32)=768 blocks (3/CU).
//         bn<16 (Q,K): x-split 2-MFMA + hi/lo split-store. bn>=16 (V): hi-only
//         + transposed f16 store. LDS 24 KB.
// MODE 1: QK^T split-K=2, split3, 256x128 tile (4 waves of 128x64: read
//         traffic 0.25 KB/MFMA vs 0.33 at 64x64 quadrants — LDS-BW is the
//         bottleneck). Grid 544 = 272 tris x 2 halves. Packed-triangular f32
//         partial store at 128-granularity; top half skipped when bn==2bm+1
//         (wave-uniform). LDS 48 KB, ~200 VGPR -> 2 blocks/CU.
// MODE 2: PV. A=P packed-triangular, B=Vt [DD,SQ], hi-only, 64x128, BK=64,
//         kend=(bmT+1)*128. grid (64,8), bm reversed = longest first. LDS 24 KB.
template<int MODE>
__global__ __launch_bounds__(256, 2)
void gemm_k(const f16* __restrict__ Ah, const f16* __restrict__ Al,
            const f16* __restrict__ Bh, const f16* __restrict__ Bl,
            float* __restrict__ Cf,
            f16* __restrict__ Qh, f16* __restrict__ Ql,
            f16* __restrict__ Kh, f16* __restrict__ Kl,
            f16* __restrict__ Vt, float scale)
{
    constexpr int TM = (MODE == 0) ? 128 : (MODE == 1) ? 256 : 64;
    constexpr int MI = (MODE == 1) ? 8 : 4;       // 16-row frags per wave
    constexpr int NI = (MODE == 2) ? 2 : 4;       // 16-col frags per wave
    constexpr int H  = (MODE == 2) ? 2 : 1;       // BK/32 half-tiles
    constexpr int AH = TM * 32;                   // f16 per A half-tile
    constexpr int BH = 128 * 32;
    constexpr bool HAS_AL = (MODE != 2);          // A-lo tile may be staged
    constexpr bool HAS_BL = (MODE == 1);          // B-lo tile staged (split3 only)
    constexpr int SMSZ = H * AH + H * BH + (HAS_AL ? H * AH : 0) + (HAS_BL ? H * BH : 0);

    int bm, bn, half = 0;
    if (MODE == 1) {
        const int lin = blockIdx.x;
        half = lin & 1;
        const int t = lin >> 1;                   // tri index in [0,272)
        bm = (int)((sqrtf(4.f * (float)t + 1.f) - 1.f) * 0.5f);
        while ((bm + 1) * (bm + 2) <= t) ++bm;    // start(bm)=bm^2+bm
        while (bm * bm + bm > t) --bm;
        bn = t - bm * bm - bm;                    // bn in [0, 2bm+2)
    } else if (MODE == 2) {
        bm = 63 - (int)blockIdx.x;                // longest blocks first
        bn = blockIdx.y;
    } else {
        bn = blockIdx.x; bm = blockIdx.y;
    }

    const int m0 = bm * TM;
    const int n0 = bn << 7;
    const int lda = (MODE == 2) ? 128 : DD;       // MODE2 A = packed tile rows
    const int ldb = (MODE == 2) ? SQ : DD;
    const int kst = (MODE == 1) ? (half << 9) : 0;
    const int kend = (MODE == 1) ? (kst + 512)
                   : (MODE == 2) ? (((bm >> 1) + 1) << 7) : DD;
    const bool aLo = (MODE == 1) || (MODE == 0 && bn < 16);

    __shared__ f16 sm[SMSZ];
    f16* smA  = sm;
    f16* smB  = sm + H * AH;
    f16* smAl = smB + H * BH;                     // valid iff HAS_AL
    f16* smBl = smAl + (HAS_AL ? H * AH : 0);     // valid iff HAS_BL

    const int tid = threadIdx.x;
    const int w = tid >> 6, lane = tid & 63;
    const int wr = (MODE == 0) ? ((w >> 1) << 6)
                 : (MODE == 1) ? ((w >> 1) << 7) : 0;
    const int wc = (MODE == 2) ? (w << 5) : ((w & 1) << 6);
    const int fcol = lane & 15, quad = lane >> 4;

    f32x4 acc[MI][NI];
#pragma unroll
    for (int i = 0; i < MI; ++i)
#pragma unroll
        for (int j = 0; j < NI; ++j) acc[i][j] = (f32x4){0.f, 0.f, 0.f, 0.f};

    const int bmT = (MODE == 2) ? (bm >> 1) : 0;
    const size_t triRow = (MODE == 2) ? (size_t)(bmT * (bmT + 1) / 2) : 0;
    const f16* Bb  = Bh + (size_t)n0 * ldb;
    const f16* Abl = (HAS_AL && aLo) ? Al + (size_t)m0 * DD : nullptr;
    const f16* Bbl = HAS_BL ? Bl + (size_t)n0 * ldb : nullptr;

    for (int k0 = kst; k0 < kend; k0 += 32 * H) {
        __syncthreads();                          // prev iter's ds_reads done
#pragma unroll
        for (int h = 0; h < H; ++h) {
            const int kk = k0 + 32 * h;
            const f16* as;
            if (MODE == 2) {
                as = Ah + ((triRow + (size_t)(kk >> 7)) << 14)
                        + ((size_t)(m0 & 127) << 7) + (kk & 127);
            } else {
                as = Ah + (size_t)m0 * DD + kk;
            }
            stage<TM / 4>(as, lda, smA + h * AH, w, lane);
            stage<32>(Bb + kk, ldb, smB + h * BH, w, lane);
            if (HAS_AL && aLo) stage<TM / 4>(Abl + kk, DD, smAl + h * AH, w, lane);
            if (HAS_BL)        stage<32>(Bbl + kk, ldb, smBl + h * BH, w, lane);
        }
        __syncthreads();                          // vmcnt drained -> LDS valid

#pragma unroll
        for (int h = 0; h < H; ++h) {
            f16x8 bh[NI], bl[NI];
#pragma unroll
            for (int in = 0; in < NI; ++in) {
                const int off = ((wc + (in << 4) + fcol) << 5) + (quad << 3);
                bh[in] = *(const f16x8*)&smB[h * BH + off];
                if (HAS_BL) bl[in] = *(const f16x8*)&smBl[h * BH + off];
            }
#pragma unroll
            for (int im = 0; im < MI; ++im) {
                const int off = ((wr + (im << 4) + fcol) << 5) + (quad << 3);
                f16x8 ah = *(const f16x8*)&smA[h * AH + off];
                f16x8 al;
                if (HAS_AL && aLo) al = *(const f16x8*)&smAl[h * AH + off];
#pragma unroll
                for (int in = 0; in < NI; ++in) {
                    if (HAS_BL)
                        acc[im][in] = __builtin_amdgcn_mfma_f32_16x16x32_f16(ah, bl[in], acc[im][in], 0, 0, 0);
                    if (HAS_AL && aLo)
                        acc[im][in] = __builtin_amdgcn_mfma_f32_16x16x32_f16(al, bh[in], acc[im][in], 0, 0, 0);
                    acc[im][in] = __builtin_amdgcn_mfma_f32_16x16x32_f16(ah, bh[in], acc[im][in], 0, 0, 0);
                }
            }
        }
    }

    // C/D layout: col = lane&15, row = quad*4 + r  [m89-verified]
    if (MODE == 0) {
#pragma unroll
        for (int im = 0; im < MI; ++im) {
#pragma unroll
            for (int in = 0; in < NI; ++in) {
                const int region = bn >> 3;                       // 0=Q 1=K 2=V
                const int colL = ((bn & 7) << 7) + wc + (in << 4) + fcol;
                if (region == 2) {
                    const int tc = m0 + wr + (im << 4) + (quad << 2);
                    f16x4 o;
#pragma unroll
                    for (int r = 0; r < 4; ++r) o[r] = (f16)acc[im][in][r];
                    *(f16x4*)&Vt[(size_t)colL * SQ + tc] = o;
                } else {
                    f16* Hh = region ? Kh : Qh;
                    f16* Hl = region ? Kl : Ql;
#pragma unroll
                    for (int r = 0; r < 4; ++r) {
                        const int row = m0 + wr + (im << 4) + (quad << 2) + r;
                        const float v = acc[im][in][r];
                        const f16 h = (f16)v;
                        Hh[(size_t)row * DD + colL] = h;
                        Hl[(size_t)row * DD + colL] = (f16)(v - (float)h);
                    }
                }
            }
        }
    } else if (MODE == 1) {
        const int R = (bm << 1) + (w >> 1);       // this wave's 128-tile row
        if (bn <= R) {                            // skip strictly-upper half-tile
            const int slot = ((R * (R + 1)) >> 1) + bn;
            float* Cp = Cf + (((size_t)half * TRI + slot) << 14);
#pragma unroll
            for (int im = 0; im < MI; ++im) {
#pragma unroll
                for (int in = 0; in < NI; ++in) {
                    const int cl = wc + (in << 4) + fcol;
#pragma unroll
                    for (int r = 0; r < 4; ++r) {
                        const int rloc = (im << 4) + (quad << 2) + r;   // 0..127
                        Cp[(rloc << 7) + cl] = acc[im][in][r] * scale;
                    }
                }
            }
        }
    } else {
#pragma unroll
        for (int im = 0; im < MI; ++im) {
#pragma unroll
            for (int in = 0; in < NI; ++in) {
#pragma unroll
                for (int r = 0; r < 4; ++r) {
                    const int row = m0 + wr + (im << 4) + (quad << 2) + r;
                    const int col = n0 + wc + (in << 4) + fcol;
                    Cf[(size_t)row * DD + col] = acc[im][in][r];
                }
            }
        }
    }
}

// Fused pre-pass: blocks [0,4096) split x into f16 hi/lo; blocks [4096,4864)
// transpose the 3 weight matrices into one [3072,1024] f16 buffer (hi only).
__global__ __launch_bounds__(256)
void prepass(const float* __restrict__ x,
             const float* __restrict__ W0, const float* __restrict__ W1,
             const float* __restrict__ W2,
             f16* __restrict__ xh, f16* __restrict__ xl,
             f16* __restrict__ Th0)
{
    __shared__ float t[64][65];
    const int id = blockIdx.x;
    const int tid = threadIdx.x;

    if (id < 4096) {
        const int i = (id * 256 + tid) * 4;
        const float4 v = *(const float4*)(x + i);
        const f16 h0 = (f16)v.x, h1 = (f16)v.y, h2 = (f16)v.z, h3 = (f16)v.w;
        f16x4 hv = {h0, h1, h2, h3};
        f16x4 lv = {(f16)(v.x - (float)h0), (f16)(v.y - (float)h1),
                    (f16)(v.z - (float)h2), (f16)(v.w - (float)h3)};
        *(f16x4*)(xh + i) = hv;
        *(f16x4*)(xl + i) = lv;
        return;
    }

    const int tt = id - 4096;
    const int z = tt >> 8, r8 = tt & 255;
    const float* W = (z == 0) ? W0 : (z == 1) ? W1 : W2;
    f16* Th = Th0 + (size_t)z * DD * DD;
    const int n0 = (r8 & 15) << 6, k0 = (r8 >> 4) << 6;
    const int tx = tid & 63, ty = tid >> 6;
    for (int r = ty; r < 64; r += 4) t[r][tx] = W[(size_t)(k0 + r) * DD + n0 + tx];
    __syncthreads();
    for (int r = ty; r < 64; r += 4)
        Th[(size_t)(n0 + r) * DD + k0 + tx] = (f16)t[tx][r];
}

// Row-wise causal softmax over packed-triangular split-K partials, vectorized:
// float4 loads of both partials, f16x4 P stores.
__global__ __launch_bounds__(256)
void softmax_causal(const float* __restrict__ A0, f16* __restrict__ P)
{
    const int i = blockIdx.x;
    const int n = i + 1;
    const int tid = threadIdx.x, w = tid >> 6, lane = tid & 63;
    __shared__ float redM[4], redS[4];
    __shared__ float rowbuf[SQ];                 // 16 KB merged-logit stash

    const int bmI = i >> 7;
    const size_t base = ((size_t)(bmI * (bmI + 1) / 2) << 14) + ((size_t)(i & 127) << 7);
    const float* A1 = A0 + ((size_t)TRI << 14);

    const int nv = n >> 2;                       // full float4 groups
    float m = -INFINITY;
    for (int g = tid; g < nv; g += 256) {
        const int j = g << 2;
        const size_t a = base + ((size_t)(j >> 7) << 14) + (j & 127);
        const float4 v0 = *(const float4*)(A0 + a);
        const float4 v1 = *(const float4*)(A1 + a);
        float4 v = make_float4(v0.x + v1.x, v0.y + v1.y, v0.z + v1.z, v0.w + v1.w);
        *(f32x4*)&rowbuf[j] = (f32x4){v.x, v.y, v.z, v.w};
        m = fmaxf(m, fmaxf(fmaxf(v.x, v.y), fmaxf(v.z, v.w)));
    }
    for (int j = (nv << 2) + tid; j < n; j += 256) {
        const size_t a = base + ((size_t)(j >> 7) << 14) + (j & 127);
        const float v = A0[a] + A1[a];
        rowbuf[j] = v;
        m = fmaxf(m, v);
    }
    m = waveMax(m);
    if (lane == 0) redM[w] = m;
    __syncthreads();
    const float mAll = fmaxf(fmaxf(redM[0], redM[1]), fmaxf(redM[2], redM[3]));

    float s = 0.f;
    for (int g = tid; g < nv; g += 256) {
        const int j = g << 2;
        f32x4 v = *(f32x4*)&rowbuf[j];
        v[0] = __expf(v[0] - mAll); v[1] = __expf(v[1] - mAll);
        v[2] = __expf(v[2] - mAll); v[3] = __expf(v[3] - mAll);
        *(f32x4*)&rowbuf[j] = v;
        s += v[0] + v[1] + v[2] + v[3];
    }
    for (int j = (nv << 2) + tid; j < n; j += 256) {
        const float e = __expf(rowbuf[j] - mAll);
        rowbuf[j] = e;
        s += e;
    }
    s = waveSum(s);
    if (lane == 0) redS[w] = s;
    __syncthreads();
    const float inv = 1.0f / (redS[0] + redS[1] + redS[2] + redS[3]);

    const int kmax = (bmI + 1) << 7;             // P zero-fill boundary
    for (int g = tid; g < nv; g += 256) {
        const int j = g << 2;
        const size_t a = base + ((size_t)(j >> 7) << 14) + (j & 127);
        const f32x4 v = *(const f32x4*)&rowbuf[j];
        f16x4 o = {(f16)(v[0] * inv), (f16)(v[1] * inv),
                   (f16)(v[2] * inv), (f16)(v[3] * inv)};
        *(f16x4*)&P[a] = o;
    }
    for (int j = (nv << 2) + tid; j < kmax; j += 256) {
        const size_t a = base + ((size_t)(j >> 7) << 14) + (j & 127);
        P[a] = (j < n) ? (f16)(rowbuf[j] * inv) : (f16)0.f;
    }
}

extern "C" void kernel_launch(void* const* d_in, const int* in_sizes, int n_in,
                              void* d_out, int out_size, void* d_ws, size_t ws_size,
                              hipStream_t stream)
{
    const float* x  = (const float*)d_in[0];
    const float* Wq = (const float*)d_in[1];
    const float* Wk = (const float*)d_in[2];
    const float* Wv = (const float*)d_in[3];
    float* out = (float*)d_out;

    // workspace carve (~149 MB)
    char* p = (char*)d_ws;
    auto take = [&](size_t bytes) { void* r = (void*)p; p += (bytes + 255) & ~(size_t)255; return r; };
    const size_t SD = (size_t)SQ * DD;          // 4M elems
    f16* xh  = (f16*)take(SD * 2);
    f16* xl  = (f16*)take(SD * 2);
    f16* Wth = (f16*)take((size_t)3 * DD * DD * 2);   // [3072][1024], hi only
    f16* Qh  = (f16*)take(SD * 2);
    f16* Ql  = (f16*)take(SD * 2);
    f16* Kh  = (f16*)take(SD * 2);
    f16* Kl  = (f16*)take(SD * 2);
    f16* Vt  = (f16*)take(SD * 2);              // [DD][SQ]
    float* attn = (float*)take((size_t)2 * TRI * 16384 * 4);  // split-K partials, packed
    f16* P   = (f16*)take((size_t)TRI * 16384 * 2);           // packed triangular

    const dim3 blk(256);

    prepass<<<dim3(4096 + 768), blk, 0, stream>>>(x, Wq, Wk, Wv, xh, xl, Wth);

    // Merged QKV projection: 768 blocks, BK=32, x-split 2-MFMA (W plain f16)
    gemm_k<0><<<dim3(24, SQ / 128), blk, 0, stream>>>(
        xh, xl, Wth, nullptr, nullptr, Qh, Ql, Kh, Kl, Vt, 1.0f);

    // attn partials = Q @ K^T / 32 : split-K=2, split3, 256x128 tiles,
    // 544 blocks = 272 tris x 2 halves
    gemm_k<1><<<dim3(544), blk, 0, stream>>>(
        Qh, Ql, Kh, Kl, attn, nullptr, nullptr, nullptr, nullptr, nullptr, 0.03125f);

    softmax_causal<<<dim3(SQ), blk, 0, stream>>>(attn, P);

    // out = P @ V : grid (64,8), longest-first
    gemm_k<2><<<dim3(SQ / 64, DD / 128), blk, 0, stream>>>(
        P, nullptr, Vt, nullptr, out, nullptr, nullptr, nullptr, nullptr, nullptr, 1.0f);
}